// Round 2
// baseline (317.819 us; speedup 1.0000x reference)
//
#include <hip/hip_runtime.h>
#include <cstdint>
#include <cstddef>

#define NB 4
#define CH 256
#define SS 4096
#define EE 128
#define QSCALE 0.08838834764831845f /* 1/sqrt(128) */

typedef __attribute__((ext_vector_type(8))) short bfrag;   // 8 bf16 = 4 VGPR
typedef __attribute__((ext_vector_type(4))) float f32x4;   // MFMA accumulator

__device__ __forceinline__ unsigned short f2bf(float f) {
  union { float f; unsigned int u; } v; v.f = f;
  unsigned int u = v.u;
  unsigned int r = u + 0x7FFFu + ((u >> 16) & 1u);  // RNE
  return (unsigned short)(r >> 16);
}

// ---------------------------------------------------------------------------
// Pass 0: fp32 -> bf16 conversion (x and the three weight matrices)
// ---------------------------------------------------------------------------
__global__ __launch_bounds__(256) void cvt_bf16(
    const float* __restrict__ src, unsigned short* __restrict__ dst, int n4)
{
  const int i = blockIdx.x * 256 + threadIdx.x;
  if (i < n4) {
    float4 v = reinterpret_cast<const float4*>(src)[i];
    ushort4 o;
    o.x = f2bf(v.x); o.y = f2bf(v.y); o.z = f2bf(v.z); o.w = f2bf(v.w);
    reinterpret_cast<ushort4*>(dst)[i] = o;
  }
}

// ---------------------------------------------------------------------------
// Pass 1: Qt[n][s][e] = (1/sqrt(E)) * sum_c theta_w[e][c] * x[n][c][s]
//         Kt[n][s][e] =              sum_c phi_w[e][c]   * x[n][c][s]
// Block: 256 thr, tile = 64 s-rows. x tile transposed through LDS so the
// MFMA A-fragment (A[m=s][k=c]) is a contiguous 16B ds_read.
// ---------------------------------------------------------------------------
__global__ __launch_bounds__(256) void pass1_qk(
    const unsigned short* __restrict__ xb,
    const unsigned short* __restrict__ thw,
    const unsigned short* __restrict__ phw,
    unsigned short* __restrict__ Qt,
    unsigned short* __restrict__ Kt)
{
  __shared__ unsigned short xT[64][CH + 8];  // +8 bf16 pad
  const int t  = threadIdx.x;
  const int n  = blockIdx.y;
  const int s0 = blockIdx.x * 64;

  // stage x^T tile: coalesced reads along s, transposed writes into LDS
  {
    const int soff = (t & 15) * 4;
    const int c0   = t >> 4;
    const ushort4* xv = reinterpret_cast<const ushort4*>(
        xb + ((size_t)n * CH) * SS + s0);
    #pragma unroll
    for (int ci = 0; ci < 16; ++ci) {
      const int c = c0 + ci * 16;
      ushort4 v = xv[c * (SS / 4) + (soff >> 2)];
      xT[soff + 0][c] = v.x;
      xT[soff + 1][c] = v.y;
      xT[soff + 2][c] = v.z;
      xT[soff + 3][c] = v.w;
    }
  }
  __syncthreads();

  const int w    = t >> 6;
  const int lane = t & 63;
  const int q    = lane >> 4;
  const int mr   = lane & 15;

  // A fragments from LDS: A[m = mr][k = c], wave w owns s-rows w*16..w*16+15
  bfrag a[8];
  {
    const bfrag* rp = reinterpret_cast<const bfrag*>(&xT[w * 16 + mr][0]);
    #pragma unroll
    for (int k = 0; k < 8; ++k) a[k] = rp[k * 4 + q];
  }

  const unsigned short* Ws[2] = { thw, phw };
  unsigned short*       Os[2] = { Qt, Kt };
  #pragma unroll
  for (int wi = 0; wi < 2; ++wi) {
    const bfrag* wp = reinterpret_cast<const bfrag*>(Ws[wi]);
    const float  sc = (wi == 0) ? QSCALE : 1.0f;
    #pragma unroll
    for (int nt = 0; nt < 8; ++nt) {
      f32x4 acc = {0.f, 0.f, 0.f, 0.f};
      #pragma unroll
      for (int k = 0; k < 8; ++k) {
        // B[k=c][n=e] fragment = W[e=nt*16+mr][c=32k+8q+j]: contiguous 16B
        bfrag b = wp[(nt * 16 + mr) * (CH / 8) + k * 4 + q];
        acc = __builtin_amdgcn_mfma_f32_16x16x32_bf16(a[k], b, acc, 0, 0, 0);
      }
      unsigned short* o = Os[wi];
      #pragma unroll
      for (int i = 0; i < 4; ++i) {
        const int srow = s0 + w * 16 + q * 4 + i;
        o[((size_t)n * SS + srow) * EE + nt * 16 + mr] = f2bf(acc[i] * sc);
      }
    }
  }
}

// ---------------------------------------------------------------------------
// Pass 2: flash attention, 64-query tile per block, 128-key tiles.
//   S = Qt @ Kt^T (scale pre-folded) -> LDS fp32 -> online softmax -> P bf16
//   O += P @ V, with V[t][c] = xb[n][c][t] streamed from global (16B frags).
// Output Yt[n][s][c] bf16.
// ---------------------------------------------------------------------------
__global__ __launch_bounds__(256) void pass2_attn(
    const unsigned short* __restrict__ Qt,
    const unsigned short* __restrict__ Kt,
    const unsigned short* __restrict__ xb,
    unsigned short* __restrict__ Yt)
{
  __shared__ float          S_lds[64][132];   // +4 pad
  __shared__ unsigned short P_lds[64][136];   // +8 pad (16B-aligned rows)
  __shared__ float row_m[64], row_l[64], row_alpha[64];

  const int t    = threadIdx.x;
  const int n    = blockIdx.y;
  const int s0   = blockIdx.x * 64;
  const int w    = t >> 6;
  const int lane = t & 63;
  const int q    = lane >> 4;
  const int mr   = lane & 15;

  if (t < 64) { row_m[t] = -INFINITY; row_l[t] = 0.f; }

  // Q fragments (64 rows x 128 e), registers for the whole key loop
  bfrag qa[4][4];
  #pragma unroll
  for (int ms = 0; ms < 4; ++ms) {
    const bfrag* rp = reinterpret_cast<const bfrag*>(
        Qt + ((size_t)n * SS + s0 + ms * 16 + mr) * EE);
    #pragma unroll
    for (int k = 0; k < 4; ++k) qa[ms][k] = rp[k * 4 + q];
  }

  f32x4 o_acc[4][4];
  #pragma unroll
  for (int ms = 0; ms < 4; ++ms)
    #pragma unroll
    for (int nt = 0; nt < 4; ++nt) o_acc[ms][nt] = (f32x4){0.f, 0.f, 0.f, 0.f};

  for (int t0 = 0; t0 < SS; t0 += 128) {
    // ---- QK^T: wave w computes key sub-tile columns 2w, 2w+1 ----
    #pragma unroll
    for (int kn2 = 0; kn2 < 2; ++kn2) {
      const int kn = w * 2 + kn2;
      bfrag kb[4];
      const bfrag* rp = reinterpret_cast<const bfrag*>(
          Kt + ((size_t)n * SS + t0 + kn * 16 + mr) * EE);
      #pragma unroll
      for (int k = 0; k < 4; ++k) kb[k] = rp[k * 4 + q];
      #pragma unroll
      for (int ms = 0; ms < 4; ++ms) {
        f32x4 acc = {0.f, 0.f, 0.f, 0.f};
        #pragma unroll
        for (int k = 0; k < 4; ++k)
          acc = __builtin_amdgcn_mfma_f32_16x16x32_bf16(qa[ms][k], kb[k], acc, 0, 0, 0);
        #pragma unroll
        for (int i = 0; i < 4; ++i)
          S_lds[ms * 16 + q * 4 + i][kn * 16 + mr] = acc[i];
      }
    }
    __syncthreads();

    // ---- online softmax on the 64x128 tile: 4 lanes per row ----
    {
      const int r  = t >> 2;
      const int cg = t & 3;
      float vmax = -INFINITY;
      #pragma unroll
      for (int j = 0; j < 32; ++j)
        vmax = fmaxf(vmax, S_lds[r][cg * 32 + j]);
      vmax = fmaxf(vmax, __shfl_xor(vmax, 1, 4));
      vmax = fmaxf(vmax, __shfl_xor(vmax, 2, 4));
      const float m_old = row_m[r];
      const float m_new = fmaxf(m_old, vmax);
      float sum = 0.f;
      #pragma unroll
      for (int j = 0; j < 32; ++j) {
        float p = __expf(S_lds[r][cg * 32 + j] - m_new);
        sum += p;
        P_lds[r][cg * 32 + j] = f2bf(p);
      }
      sum += __shfl_xor(sum, 1, 4);
      sum += __shfl_xor(sum, 2, 4);
      if (cg == 0) {
        const float al = __expf(m_old - m_new);  // exp(-inf)=0 on iter 0
        row_alpha[r] = al;
        row_m[r]     = m_new;
        row_l[r]     = row_l[r] * al + sum;
      }
    }
    __syncthreads();

    // ---- rescale O, then O += P @ V ----
    float al[4][4];
    #pragma unroll
    for (int ms = 0; ms < 4; ++ms)
      #pragma unroll
      for (int i = 0; i < 4; ++i)
        al[ms][i] = row_alpha[ms * 16 + q * 4 + i];
    #pragma unroll
    for (int ms = 0; ms < 4; ++ms)
      #pragma unroll
      for (int nt = 0; nt < 4; ++nt)
        #pragma unroll
        for (int i = 0; i < 4; ++i)
          o_acc[ms][nt][i] *= al[ms][i];

    #pragma unroll
    for (int kk = 0; kk < 4; ++kk) {
      bfrag pa[4];
      #pragma unroll
      for (int ms = 0; ms < 4; ++ms) {
        const bfrag* pp = reinterpret_cast<const bfrag*>(&P_lds[ms * 16 + mr][0]);
        pa[ms] = pp[kk * 4 + q];
      }
      #pragma unroll
      for (int nt = 0; nt < 4; ++nt) {
        const int c = w * 64 + nt * 16 + mr;
        // B[k=t][n=c] fragment = xb[n][c][t0+32kk+8q+j]: contiguous 16B
        const bfrag* vp = reinterpret_cast<const bfrag*>(
            xb + ((size_t)n * CH + c) * SS + t0);
        bfrag vb = vp[kk * 4 + q];
        #pragma unroll
        for (int ms = 0; ms < 4; ++ms)
          o_acc[ms][nt] = __builtin_amdgcn_mfma_f32_16x16x32_bf16(
              pa[ms], vb, o_acc[ms][nt], 0, 0, 0);
      }
    }
  }

  // ---- epilogue: divide by l, write Yt[s][c] ----
  #pragma unroll
  for (int ms = 0; ms < 4; ++ms) {
    float inv[4];
    #pragma unroll
    for (int i = 0; i < 4; ++i) inv[i] = 1.0f / row_l[ms * 16 + q * 4 + i];
    #pragma unroll
    for (int nt = 0; nt < 4; ++nt) {
      const int c = w * 64 + nt * 16 + mr;
      #pragma unroll
      for (int i = 0; i < 4; ++i) {
        const int s = s0 + ms * 16 + q * 4 + i;
        Yt[((size_t)n * SS + s) * CH + c] = f2bf(o_acc[ms][nt][i] * inv[i]);
      }
    }
  }
}

// ---------------------------------------------------------------------------
// Pass 3: out[n][o][s] = x[n][o][s] + sum_c proj_w[o][c] * Yt[n][s][c]
// fp32 residual read + fp32 store. Block tile: 64 o x 64 s.
// ---------------------------------------------------------------------------
__global__ __launch_bounds__(256) void pass3_proj(
    const unsigned short* __restrict__ Yt,
    const unsigned short* __restrict__ pw,
    const float* __restrict__ x,
    float* __restrict__ out)
{
  const int t    = threadIdx.x;
  const int w    = t >> 6;
  const int lane = t & 63;
  const int q    = lane >> 4;
  const int mr   = lane & 15;
  const int n    = blockIdx.z;
  const int o0   = blockIdx.y * 64 + w * 16;
  const int s1   = blockIdx.x * 64;

  bfrag a[8];
  {
    const bfrag* ap = reinterpret_cast<const bfrag*>(pw + (o0 + mr) * CH);
    #pragma unroll
    for (int k = 0; k < 8; ++k) a[k] = ap[k * 4 + q];
  }

  #pragma unroll
  for (int nt = 0; nt < 4; ++nt) {
    f32x4 acc = {0.f, 0.f, 0.f, 0.f};
    const bfrag* bp = reinterpret_cast<const bfrag*>(
        Yt + ((size_t)n * SS + s1 + nt * 16 + mr) * CH);
    #pragma unroll
    for (int k = 0; k < 8; ++k)
      acc = __builtin_amdgcn_mfma_f32_16x16x32_bf16(a[k], bp[k * 4 + q], acc, 0, 0, 0);
    #pragma unroll
    for (int i = 0; i < 4; ++i) {
      const int o = o0 + q * 4 + i;
      const int s = s1 + nt * 16 + mr;
      const size_t idx = ((size_t)n * CH + o) * SS + s;
      out[idx] = x[idx] + acc[i];
    }
  }
}

// ---------------------------------------------------------------------------
extern "C" void kernel_launch(void* const* d_in, const int* in_sizes, int n_in,
                              void* d_out, int out_size, void* d_ws, size_t ws_size,
                              hipStream_t stream) {
  const float* x   = (const float*)d_in[0];
  const float* thw = (const float*)d_in[1];
  const float* phw = (const float*)d_in[2];
  const float* pw  = (const float*)d_in[3];
  float* out = (float*)d_out;

  // workspace layout (bf16 elements)
  unsigned short* xb   = (unsigned short*)d_ws;               // 8 MB
  unsigned short* Yt   = xb + (size_t)NB * CH * SS;           // 8 MB
  unsigned short* Qt   = Yt + (size_t)NB * CH * SS;           // 4 MB
  unsigned short* Kt   = Qt + (size_t)NB * SS * EE;           // 4 MB
  unsigned short* thwb = Kt + (size_t)NB * SS * EE;           // 64 KB
  unsigned short* phwb = thwb + EE * CH;                      // 64 KB
  unsigned short* pwb  = phwb + EE * CH;                      // 128 KB

  const int nx4 = NB * CH * SS / 4;   // 1,048,576
  const int nw4 = EE * CH / 4;        // 8,192
  const int np4 = CH * CH / 4;        // 16,384
  cvt_bf16<<<(nx4 + 255) / 256, 256, 0, stream>>>(x,   xb,   nx4);
  cvt_bf16<<<(nw4 + 255) / 256, 256, 0, stream>>>(thw, thwb, nw4);
  cvt_bf16<<<(nw4 + 255) / 256, 256, 0, stream>>>(phw, phwb, nw4);
  cvt_bf16<<<(np4 + 255) / 256, 256, 0, stream>>>(pw,  pwb,  np4);

  pass1_qk  <<<dim3(SS / 64, NB),          256, 0, stream>>>(xb, thwb, phwb, Qt, Kt);
  pass2_attn<<<dim3(SS / 64, NB),          256, 0, stream>>>(Qt, Kt, xb, Yt);
  pass3_proj<<<dim3(SS / 64, CH / 64, NB), 256, 0, stream>>>(Yt, pwb, x, out);
}

// Round 3
// 215.653 us; speedup vs baseline: 1.4737x; 1.4737x over previous
//
#include <hip/hip_runtime.h>
#include <cstdint>
#include <cstddef>

#define NB 4
#define CH 256
#define SS 4096
#define EE 128
#define QSCALE 0.08838834764831845f /* 1/sqrt(128) */

typedef __attribute__((ext_vector_type(8))) short bfrag;          // 8 bf16 = 4 VGPR
typedef __attribute__((ext_vector_type(8))) unsigned short u16x8; // 16B store
typedef __attribute__((ext_vector_type(4))) float f32x4;          // MFMA acc

__device__ __forceinline__ unsigned short f2bf(float f) {
  union { float f; unsigned int u; } v; v.f = f;
  unsigned int u = v.u;
  unsigned int r = u + 0x7FFFu + ((u >> 16) & 1u);  // RNE
  return (unsigned short)(r >> 16);
}

// ---------------------------------------------------------------------------
// Pass 0: fused fp32 -> bf16 conversion of x + the three weight matrices
// ---------------------------------------------------------------------------
__global__ __launch_bounds__(256) void cvt_all(
    const float* __restrict__ x,   const float* __restrict__ thw,
    const float* __restrict__ phw, const float* __restrict__ pw,
    unsigned short* __restrict__ xb,   unsigned short* __restrict__ thwb,
    unsigned short* __restrict__ phwb, unsigned short* __restrict__ pwb)
{
  const int nx4 = NB * CH * SS / 4;
  const int nw4 = EE * CH / 4;
  const int np4 = CH * CH / 4;
  int i = blockIdx.x * 256 + threadIdx.x;
  const float* src; unsigned short* dst; int off;
  if      (i < nx4)                 { src = x;   dst = xb;   off = i; }
  else if (i < nx4 + nw4)           { src = thw; dst = thwb; off = i - nx4; }
  else if (i < nx4 + 2 * nw4)       { src = phw; dst = phwb; off = i - nx4 - nw4; }
  else if (i < nx4 + 2 * nw4 + np4) { src = pw;  dst = pwb;  off = i - nx4 - 2 * nw4; }
  else return;
  float4 v = reinterpret_cast<const float4*>(src)[off];
  ushort4 o;
  o.x = f2bf(v.x); o.y = f2bf(v.y); o.z = f2bf(v.z); o.w = f2bf(v.w);
  reinterpret_cast<ushort4*>(dst)[off] = o;
}

// ---------------------------------------------------------------------------
// Pass 1: z=0: Qt[n][s][e] = QSCALE * sum_c theta_w[e][c] * x[n][c][s]
//         z=1: Kt[n][s][e] =          sum_c phi_w[e][c]   * x[n][c][s]
// Grid (SS/64, NB, 2): 512 blocks -> 2 blocks/CU.
// ---------------------------------------------------------------------------
__global__ __launch_bounds__(256) void pass1_qk(
    const unsigned short* __restrict__ xb,
    const unsigned short* __restrict__ thw,
    const unsigned short* __restrict__ phw,
    unsigned short* __restrict__ Qt,
    unsigned short* __restrict__ Kt)
{
  __shared__ unsigned short xT[64][CH + 8];
  const int t  = threadIdx.x;
  const int n  = blockIdx.y;
  const int s0 = blockIdx.x * 64;
  const int z  = blockIdx.z;

  // stage x^T tile: coalesced reads along s, transposed writes into LDS
  {
    const int soff = (t & 15) * 4;
    const int c0   = t >> 4;
    const ushort4* xv = reinterpret_cast<const ushort4*>(
        xb + ((size_t)n * CH) * SS + s0);
    #pragma unroll
    for (int ci = 0; ci < 16; ++ci) {
      const int c = c0 + ci * 16;
      ushort4 v = xv[c * (SS / 4) + (soff >> 2)];
      xT[soff + 0][c] = v.x;
      xT[soff + 1][c] = v.y;
      xT[soff + 2][c] = v.z;
      xT[soff + 3][c] = v.w;
    }
  }
  __syncthreads();

  const int w    = t >> 6;
  const int lane = t & 63;
  const int q    = lane >> 4;
  const int mr   = lane & 15;

  bfrag a[8];
  {
    const bfrag* rp = reinterpret_cast<const bfrag*>(&xT[w * 16 + mr][0]);
    #pragma unroll
    for (int k = 0; k < 8; ++k) a[k] = rp[k * 4 + q];
  }

  const unsigned short* wsel = z ? phw : thw;
  unsigned short*       osel = z ? Kt  : Qt;
  const float           sc   = z ? 1.0f : QSCALE;
  const bfrag* wp = reinterpret_cast<const bfrag*>(wsel);
  #pragma unroll
  for (int nt = 0; nt < 8; ++nt) {
    f32x4 acc = {0.f, 0.f, 0.f, 0.f};
    #pragma unroll
    for (int k = 0; k < 8; ++k) {
      bfrag b = wp[(nt * 16 + mr) * (CH / 8) + k * 4 + q];
      acc = __builtin_amdgcn_mfma_f32_16x16x32_bf16(a[k], b, acc, 0, 0, 0);
    }
    #pragma unroll
    for (int i = 0; i < 4; ++i) {
      const int srow = s0 + w * 16 + q * 4 + i;
      osel[((size_t)n * SS + srow) * EE + nt * 16 + mr] = f2bf(acc[i] * sc);
    }
  }
}

// ---------------------------------------------------------------------------
// Pass 2: flash attention. 512 threads (8 waves), Q-tile 64, key tiles 128.
// Wave w: QK^T key cols w*16..w*16+15; PV output cols w*32..w*32+31.
// V frags prefetched at iter top; K frags for iter+1 prefetched mid-iter.
// ---------------------------------------------------------------------------
__global__ __launch_bounds__(512, 2) void pass2_attn(
    const unsigned short* __restrict__ Qt,
    const unsigned short* __restrict__ Kt,
    const unsigned short* __restrict__ xb,
    unsigned short* __restrict__ Yt)
{
  __shared__ float          S_lds[64][132];   // row stride 132 dw: 2-way on MFMA write
  __shared__ unsigned short P_lds[64][136];   // 16B-aligned rows
  __shared__ float row_m[64], row_l[64], row_alpha[64];

  const int t    = threadIdx.x;
  const int n    = blockIdx.y;
  const int s0   = blockIdx.x * 64;
  const int w    = t >> 6;      // 0..7
  const int lane = t & 63;
  const int q    = lane >> 4;
  const int mr   = lane & 15;

  if (t < 64) { row_m[t] = -INFINITY; row_l[t] = 0.f; }

  // Q fragments (64 rows x 128 e) in registers for the whole loop
  bfrag qa[4][4];
  #pragma unroll
  for (int ms = 0; ms < 4; ++ms) {
    const bfrag* rp = reinterpret_cast<const bfrag*>(
        Qt + ((size_t)n * SS + s0 + ms * 16 + mr) * EE);
    #pragma unroll
    for (int k = 0; k < 4; ++k) qa[ms][k] = rp[k * 4 + q];
  }

  f32x4 o_acc[4][2];
  #pragma unroll
  for (int ms = 0; ms < 4; ++ms)
    #pragma unroll
    for (int nt = 0; nt < 2; ++nt) o_acc[ms][nt] = (f32x4){0.f, 0.f, 0.f, 0.f};

  // K fragments for iter 0 (wave w -> key col block w)
  bfrag kb[4];
  {
    const bfrag* rp = reinterpret_cast<const bfrag*>(
        Kt + ((size_t)n * SS + w * 16 + mr) * EE);
    #pragma unroll
    for (int k = 0; k < 4; ++k) kb[k] = rp[k * 4 + q];
  }

  for (int t0 = 0; t0 < SS; t0 += 128) {
    // ---- prefetch V fragments for THIS iter (consumed after softmax) ----
    bfrag vb[4][2];
    #pragma unroll
    for (int nt = 0; nt < 2; ++nt) {
      const int c = w * 32 + nt * 16 + mr;
      const bfrag* vp = reinterpret_cast<const bfrag*>(
          xb + ((size_t)n * CH + c) * SS + t0);
      #pragma unroll
      for (int kk = 0; kk < 4; ++kk) vb[kk][nt] = vp[kk * 4 + q];
    }

    // ---- QK^T: wave w -> 16 key cols ----
    #pragma unroll
    for (int ms = 0; ms < 4; ++ms) {
      f32x4 acc = {0.f, 0.f, 0.f, 0.f};
      #pragma unroll
      for (int k = 0; k < 4; ++k)
        acc = __builtin_amdgcn_mfma_f32_16x16x32_bf16(qa[ms][k], kb[k], acc, 0, 0, 0);
      #pragma unroll
      for (int i = 0; i < 4; ++i)
        S_lds[ms * 16 + q * 4 + i][w * 16 + mr] = acc[i];
    }
    __syncthreads();

    // ---- prefetch K fragments for NEXT iter ----
    {
      const int t1 = t0 + 128;
      if (t1 < SS) {
        const bfrag* rp = reinterpret_cast<const bfrag*>(
            Kt + ((size_t)n * SS + t1 + w * 16 + mr) * EE);
        #pragma unroll
        for (int k = 0; k < 4; ++k) kb[k] = rp[k * 4 + q];
      }
    }

    // ---- online softmax: 8 lanes/row, float4 reads, ushort8 P writes ----
    {
      const int r  = t >> 3;
      const int cg = t & 7;
      const float4* srow = reinterpret_cast<const float4*>(&S_lds[r][cg * 16]);
      float4 v0 = srow[0], v1 = srow[1], v2 = srow[2], v3 = srow[3];
      float vmax = fmaxf(fmaxf(fmaxf(v0.x, v0.y), fmaxf(v0.z, v0.w)),
                         fmaxf(fmaxf(v1.x, v1.y), fmaxf(v1.z, v1.w)));
      vmax = fmaxf(vmax, fmaxf(fmaxf(fmaxf(v2.x, v2.y), fmaxf(v2.z, v2.w)),
                               fmaxf(fmaxf(v3.x, v3.y), fmaxf(v3.z, v3.w))));
      vmax = fmaxf(vmax, __shfl_xor(vmax, 1, 8));
      vmax = fmaxf(vmax, __shfl_xor(vmax, 2, 8));
      vmax = fmaxf(vmax, __shfl_xor(vmax, 4, 8));
      const float m_old = row_m[r];
      const float m_new = fmaxf(m_old, vmax);

      float p[16];
      p[0]=__expf(v0.x-m_new); p[1]=__expf(v0.y-m_new); p[2]=__expf(v0.z-m_new); p[3]=__expf(v0.w-m_new);
      p[4]=__expf(v1.x-m_new); p[5]=__expf(v1.y-m_new); p[6]=__expf(v1.z-m_new); p[7]=__expf(v1.w-m_new);
      p[8]=__expf(v2.x-m_new); p[9]=__expf(v2.y-m_new); p[10]=__expf(v2.z-m_new); p[11]=__expf(v2.w-m_new);
      p[12]=__expf(v3.x-m_new); p[13]=__expf(v3.y-m_new); p[14]=__expf(v3.z-m_new); p[15]=__expf(v3.w-m_new);
      float sum = 0.f;
      u16x8 pk0, pk1;
      #pragma unroll
      for (int j = 0; j < 8; ++j) { sum += p[j];     pk0[j] = f2bf(p[j]); }
      #pragma unroll
      for (int j = 0; j < 8; ++j) { sum += p[8 + j]; pk1[j] = f2bf(p[8 + j]); }
      *reinterpret_cast<u16x8*>(&P_lds[r][cg * 16])     = pk0;
      *reinterpret_cast<u16x8*>(&P_lds[r][cg * 16 + 8]) = pk1;
      sum += __shfl_xor(sum, 1, 8);
      sum += __shfl_xor(sum, 2, 8);
      sum += __shfl_xor(sum, 4, 8);
      if (cg == 0) {
        const float al = __expf(m_old - m_new);   // exp(-inf)=0 on iter 0
        row_alpha[r] = al;
        row_m[r]     = m_new;
        row_l[r]     = row_l[r] * al + sum;
      }
    }
    __syncthreads();

    // ---- rescale O, then O += P @ V ----
    #pragma unroll
    for (int ms = 0; ms < 4; ++ms) {
      float al[4];
      #pragma unroll
      for (int i = 0; i < 4; ++i) al[i] = row_alpha[ms * 16 + q * 4 + i];
      #pragma unroll
      for (int nt = 0; nt < 2; ++nt)
        #pragma unroll
        for (int i = 0; i < 4; ++i) o_acc[ms][nt][i] *= al[i];
    }

    #pragma unroll
    for (int kk = 0; kk < 4; ++kk) {
      bfrag pa[4];
      #pragma unroll
      for (int ms = 0; ms < 4; ++ms)
        pa[ms] = reinterpret_cast<const bfrag*>(&P_lds[ms * 16 + mr][0])[kk * 4 + q];
      #pragma unroll
      for (int nt = 0; nt < 2; ++nt)
        #pragma unroll
        for (int ms = 0; ms < 4; ++ms)
          o_acc[ms][nt] = __builtin_amdgcn_mfma_f32_16x16x32_bf16(
              pa[ms], vb[kk][nt], o_acc[ms][nt], 0, 0, 0);
    }
  }

  // ---- epilogue ----
  #pragma unroll
  for (int ms = 0; ms < 4; ++ms) {
    float inv[4];
    #pragma unroll
    for (int i = 0; i < 4; ++i) inv[i] = 1.0f / row_l[ms * 16 + q * 4 + i];
    #pragma unroll
    for (int nt = 0; nt < 2; ++nt) {
      const int c = w * 32 + nt * 16 + mr;
      #pragma unroll
      for (int i = 0; i < 4; ++i) {
        const int s = s0 + ms * 16 + q * 4 + i;
        Yt[((size_t)n * SS + s) * CH + c] = f2bf(o_acc[ms][nt][i] * inv[i]);
      }
    }
  }
}

// ---------------------------------------------------------------------------
// Pass 3: out[n][o][s] = x[n][o][s] + sum_c proj_w[o][c] * Yt[n][s][c]
// ---------------------------------------------------------------------------
__global__ __launch_bounds__(256) void pass3_proj(
    const unsigned short* __restrict__ Yt,
    const unsigned short* __restrict__ pw,
    const float* __restrict__ x,
    float* __restrict__ out)
{
  const int t    = threadIdx.x;
  const int w    = t >> 6;
  const int lane = t & 63;
  const int q    = lane >> 4;
  const int mr   = lane & 15;
  const int n    = blockIdx.z;
  const int o0   = blockIdx.y * 64 + w * 16;
  const int s1   = blockIdx.x * 64;

  bfrag a[8];
  {
    const bfrag* ap = reinterpret_cast<const bfrag*>(pw + (o0 + mr) * CH);
    #pragma unroll
    for (int k = 0; k < 8; ++k) a[k] = ap[k * 4 + q];
  }

  #pragma unroll
  for (int nt = 0; nt < 4; ++nt) {
    f32x4 acc = {0.f, 0.f, 0.f, 0.f};
    const bfrag* bp = reinterpret_cast<const bfrag*>(
        Yt + ((size_t)n * SS + s1 + nt * 16 + mr) * CH);
    #pragma unroll
    for (int k = 0; k < 8; ++k)
      acc = __builtin_amdgcn_mfma_f32_16x16x32_bf16(a[k], bp[k * 4 + q], acc, 0, 0, 0);
    #pragma unroll
    for (int i = 0; i < 4; ++i) {
      const int o = o0 + q * 4 + i;
      const int s = s1 + nt * 16 + mr;
      const size_t idx = ((size_t)n * CH + o) * SS + s;
      out[idx] = x[idx] + acc[i];
    }
  }
}

// ---------------------------------------------------------------------------
extern "C" void kernel_launch(void* const* d_in, const int* in_sizes, int n_in,
                              void* d_out, int out_size, void* d_ws, size_t ws_size,
                              hipStream_t stream) {
  const float* x   = (const float*)d_in[0];
  const float* thw = (const float*)d_in[1];
  const float* phw = (const float*)d_in[2];
  const float* pw  = (const float*)d_in[3];
  float* out = (float*)d_out;

  unsigned short* xb   = (unsigned short*)d_ws;               // 8 MB
  unsigned short* Yt   = xb + (size_t)NB * CH * SS;           // 8 MB
  unsigned short* Qt   = Yt + (size_t)NB * CH * SS;           // 4 MB
  unsigned short* Kt   = Qt + (size_t)NB * SS * EE;           // 4 MB
  unsigned short* thwb = Kt + (size_t)NB * SS * EE;           // 64 KB
  unsigned short* phwb = thwb + EE * CH;                      // 64 KB
  unsigned short* pwb  = phwb + EE * CH;                      // 128 KB

  const int nx4 = NB * CH * SS / 4;
  const int nw4 = EE * CH / 4;
  const int np4 = CH * CH / 4;
  const int tot4 = nx4 + 2 * nw4 + np4;
  cvt_all<<<(tot4 + 255) / 256, 256, 0, stream>>>(
      x, thw, phw, pw, xb, thwb, phwb, pwb);

  pass1_qk  <<<dim3(SS / 64, NB, 2),       256, 0, stream>>>(xb, thwb, phwb, Qt, Kt);
  pass2_attn<<<dim3(SS / 64, NB),          512, 0, stream>>>(Qt, Kt, xb, Yt);
  pass3_proj<<<dim3(SS / 64, CH / 64, NB), 256, 0, stream>>>(Yt, pwb, x, out);
}